// Round 4
// baseline (168.376 us; speedup 1.0000x reference)
//
#include <hip/hip_runtime.h>
#include <hip/hip_bf16.h>

// h:[N,128] f32, src/dst:[E] i32, W1:[128,256] f32, b1:[128] f32, W2:[1,128] f32,
// b2,W3,b3: scalars f32  -> out:[E] f32
// Factorization: W1@concat(h[s],h[d]) = W1[:,:128]@h[s] + W1[:,128:]@h[d]
// Stage 1 (per node, MFMA bf16): AB[n][0:128] = W1[:,:128]@h[n] + b1 ; AB[n][128:256] = W1[:,128:]@h[n]
//   AB stored bf16 in d_ws (51.2 MB) to halve stage-2 gather traffic.
// Stage 2 (per edge): out = sigmoid(relu(W3*relu(W2 . relu(A[s]+B[d]) + b2) + b3))

#define HID 128

using short8 = __attribute__((ext_vector_type(8))) short;  // 8 bf16 = 4 VGPRs
using f32x4  = __attribute__((ext_vector_type(4))) float;

typedef unsigned int uint32;

static __device__ __forceinline__ unsigned short f2bf(float f) {  // RNE f32->bf16
    uint32 u = __float_as_uint(f);
    u += 0x7fffu + ((u >> 16) & 1u);
    return (unsigned short)(u >> 16);
}
static __device__ __forceinline__ uint32 pk2(float a, float b) {
    return ((uint32)f2bf(a)) | (((uint32)f2bf(b)) << 16);
}
static __device__ __forceinline__ float bflo(uint32 u) { return __uint_as_float(u << 16); }
static __device__ __forceinline__ float bfhi(uint32 u) { return __uint_as_float(u & 0xffff0000u); }

// ---------------------------------------------------------------------------
// Stage 1: node GEMM via MFMA.  D[o][n] = sum_k V[o][k] * h[n][k]
//   V[o][k] = W1[o&127][(o>=128?128:0)+k],  o in [0,256), k in [0,128)
// mfma_f32_16x16x32_bf16 (m89-verified): A[m=lane&15][k=quad*8+j],
//   B[k=quad*8+j][n=lane&15], C/D col=lane&15 (node), row=quad*4+reg (output).
// R3 restructure (occupancy was 12.7%, latency-bound):
//   - NT_PER_BLOCK 10->4  => 1563 blocks (2.4 -> ~6 blocks/CU demanded)
//   - double-buffered LDS h tile + register prefetch of tile i+1 issued
//     before tile i's MFMA; ONE barrier per iteration.
//   Barrier safety: at the top-of-iter-i barrier every wave has finished its
//   iter i-1 reads of buf[(i-1)&1] == buf[(i+1)&1], so post-barrier writes to
//   buf[(i+1)&1] cannot race; reads of buf[i&1] are ordered by the same
//   barrier against iter i-1's writes.
// LDS layout: row r, ch-block j (8ch=16B) at r*256 + ((j^r)*8): XOR swizzle
//   -> <=2-way bank aliasing (free), 16B-aligned b128 accesses.
// ---------------------------------------------------------------------------
#define NT_PER_BLOCK 4  // 16-node tiles per block

__global__ __launch_bounds__(256) void node_stage_kernel(
    const float* __restrict__ h,     // [N,128]
    const float* __restrict__ W1,    // [128,256]
    const float* __restrict__ b1,    // [128]
    unsigned short* __restrict__ AB, // [N,256] bf16 bits out
    int N)
{
    __shared__ unsigned short hs[2][16 * 256];  // 2 x 8 KB double buffer

    const int t    = threadIdx.x;
    const int lane = t & 63;
    const int wave = t >> 6;     // 0..3 -> output group wave*64
    const int c    = lane & 15;
    const int q    = lane >> 4;

    // Loop-invariant weight A-frags (fp32 load -> bf16 frag, once per block)
    short8 vfrag[4][4];
    float  bias[4][4];
#pragma unroll
    for (int ot = 0; ot < 4; ++ot) {
#pragma unroll
        for (int ks = 0; ks < 4; ++ks) {
            int o   = wave * 64 + ot * 16 + c;
            int row = o & 127;
            int col = ((o >= 128) ? 128 : 0) + ks * 32 + q * 8;
            const float* p = W1 + row * 256 + col;
            float4 f0 = *(const float4*)p;
            float4 f1 = *(const float4*)(p + 4);
            short8 v;
            v[0] = (short)f2bf(f0.x); v[1] = (short)f2bf(f0.y);
            v[2] = (short)f2bf(f0.z); v[3] = (short)f2bf(f0.w);
            v[4] = (short)f2bf(f1.x); v[5] = (short)f2bf(f1.y);
            v[6] = (short)f2bf(f1.z); v[7] = (short)f2bf(f1.w);
            vfrag[ot][ks] = v;
        }
#pragma unroll
        for (int r = 0; r < 4; ++r) {
            int o = wave * 64 + ot * 16 + q * 4 + r;
            bias[ot][r] = (o < 128) ? b1[o] : 0.0f;
        }
    }

    const int sr = t >> 4;   // staging row 0..15
    const int sj = t & 15;   // staging ch-block 0..15
    const int ntiles = N >> 4;            // N is a multiple of 16
    const int nt0 = blockIdx.x * NT_PER_BLOCK;
    if (nt0 >= ntiles) return;

    // Prologue: load tile nt0 and stage into buffer 0.
    {
        const float* p = h + (size_t)(nt0 * 16 + sr) * HID + sj * 8;
        float4 f0 = *(const float4*)p;
        float4 f1 = *(const float4*)(p + 4);
        uint4 st;
        st.x = pk2(f0.x, f0.y);
        st.y = pk2(f0.z, f0.w);
        st.z = pk2(f1.x, f1.y);
        st.w = pk2(f1.z, f1.w);
        *(uint4*)(hs[0] + sr * 256 + ((sj ^ sr) * 8)) = st;
    }

#pragma unroll
    for (int it = 0; it < NT_PER_BLOCK; ++it) {
        const int tile = nt0 + it;
        if (tile >= ntiles) break;
        __syncthreads();

        // Issue next tile's global loads early (hide HBM latency under MFMA).
        const bool have_next = (it + 1 < NT_PER_BLOCK) && (tile + 1 < ntiles);
        float4 g0, g1;
        if (have_next) {
            const float* p = h + (size_t)((tile + 1) * 16 + sr) * HID + sj * 8;
            g0 = *(const float4*)p;
            g1 = *(const float4*)(p + 4);
        }

        short8 hfrag[4];
#pragma unroll
        for (int ks = 0; ks < 4; ++ks) {
            int blk = (ks * 4 + q) ^ c;  // xor-unswizzle
            hfrag[ks] = *(const short8*)(hs[it & 1] + c * 256 + blk * 8);
        }

        f32x4 acc[4];
#pragma unroll
        for (int ot = 0; ot < 4; ++ot) acc[ot] = (f32x4){0.f, 0.f, 0.f, 0.f};

#pragma unroll
        for (int ks = 0; ks < 4; ++ks)
#pragma unroll
            for (int ot = 0; ot < 4; ++ot)
                acc[ot] = __builtin_amdgcn_mfma_f32_16x16x32_bf16(
                    vfrag[ot][ks], hfrag[ks], acc[ot], 0, 0, 0);

        const int node = tile * 16 + c;
#pragma unroll
        for (int ot = 0; ot < 4; ++ot) {
            int o_base = wave * 64 + ot * 16 + q * 4;
            uint2 st;
            st.x = pk2(acc[ot][0] + bias[ot][0], acc[ot][1] + bias[ot][1]);
            st.y = pk2(acc[ot][2] + bias[ot][2], acc[ot][3] + bias[ot][3]);
            *(uint2*)(AB + (size_t)node * 256 + o_base) = st;
        }

        // Stage prefetched tile into the other buffer (post-barrier: safe).
        if (have_next) {
            uint4 st;
            st.x = pk2(g0.x, g0.y);
            st.y = pk2(g0.z, g0.w);
            st.z = pk2(g1.x, g1.y);
            st.w = pk2(g1.z, g1.w);
            *(uint4*)(hs[(it + 1) & 1] + sr * 256 + ((sj ^ sr) * 8)) = st;
        }
    }
}

// ---------------------------------------------------------------------------
// Stage 2: 4 edges per wave, 16 lanes per edge; lane handles 8 channels via
// one uint4 (16B) load each from A-part and B-part. Reduce = 4 xor-shuffles
// shared across the 4 edges; tail once per 16-lane group.
// ---------------------------------------------------------------------------
__global__ __launch_bounds__(256) void edge_stage_kernel(
    const unsigned short* __restrict__ AB,  // [N,256] bf16 bits
    const int* __restrict__ src,
    const int* __restrict__ dst,
    const float* __restrict__ W2,   // [128]
    const float* __restrict__ b2,   // [1]
    const float* __restrict__ W3,   // [1]
    const float* __restrict__ b3,   // [1]
    float* __restrict__ out,        // [E]
    int E)
{
    const int lane = threadIdx.x & 63;
    const int wave = threadIdx.x >> 6;
    const int sub  = lane & 15;     // lane within edge group
    const int eg   = lane >> 4;     // edge slot 0..3 in this wave
    const int e    = blockIdx.x * 16 + wave * 4 + eg;
    if (e >= E) return;

    const int s = src[e];
    const int d = dst[e];

    const uint4 ua = *(const uint4*)(AB + (size_t)s * 256 + sub * 8);
    const uint4 ub = *(const uint4*)(AB + (size_t)d * 256 + 128 + sub * 8);
    const float4 w0 = *(const float4*)(W2 + sub * 8);
    const float4 w1 = *(const float4*)(W2 + sub * 8 + 4);

    float p;
    {
        float t0 = fmaxf(bflo(ua.x) + bflo(ub.x), 0.0f);
        float t1 = fmaxf(bfhi(ua.x) + bfhi(ub.x), 0.0f);
        float t2 = fmaxf(bflo(ua.y) + bflo(ub.y), 0.0f);
        float t3 = fmaxf(bfhi(ua.y) + bfhi(ub.y), 0.0f);
        float t4 = fmaxf(bflo(ua.z) + bflo(ub.z), 0.0f);
        float t5 = fmaxf(bfhi(ua.z) + bfhi(ub.z), 0.0f);
        float t6 = fmaxf(bflo(ua.w) + bflo(ub.w), 0.0f);
        float t7 = fmaxf(bfhi(ua.w) + bfhi(ub.w), 0.0f);
        p  = t0 * w0.x;
        p  = fmaf(t1, w0.y, p);
        p  = fmaf(t2, w0.z, p);
        p  = fmaf(t3, w0.w, p);
        p  = fmaf(t4, w1.x, p);
        p  = fmaf(t5, w1.y, p);
        p  = fmaf(t6, w1.z, p);
        p  = fmaf(t7, w1.w, p);
    }

#pragma unroll
    for (int m = 8; m >= 1; m >>= 1) p += __shfl_xor(p, m, 64);

    if (sub == 0) {
        float y2 = fmaxf(p + b2[0], 0.0f);
        float y3 = fmaxf(W3[0] * y2 + b3[0], 0.0f);
        out[e] = 1.0f / (1.0f + __expf(-y3));
    }
}

// ---------------------------------------------------------------------------
// Fallback (ws too small): direct per-edge MLP, fp32. Correct, slow.
// ---------------------------------------------------------------------------
__global__ __launch_bounds__(256) void edge_direct_kernel(
    const float* __restrict__ h,
    const int* __restrict__ src,
    const int* __restrict__ dst,
    const float* __restrict__ W1,
    const float* __restrict__ b1,
    const float* __restrict__ W2,
    const float* __restrict__ b2,
    const float* __restrict__ W3,
    const float* __restrict__ b3,
    float* __restrict__ out,
    int E)
{
    __shared__ float x[256];
    __shared__ float red[4];
    const int e = blockIdx.x;
    if (e >= E) return;
    const int t = threadIdx.x;
    const int s = src[e];
    const int d = dst[e];

    if (t < 128) x[t] = h[(size_t)s * HID + t];
    else         x[t] = h[(size_t)d * HID + (t - 128)];
    __syncthreads();

    float contrib = 0.0f;
    if (t < 128) {
        float acc = b1[t];
        const float* wr = W1 + t * 256;
        for (int k = 0; k < 256; ++k) acc = fmaf(wr[k], x[k], acc);
        contrib = fmaxf(acc, 0.0f) * W2[t];
    }
#pragma unroll
    for (int m = 32; m >= 1; m >>= 1) contrib += __shfl_xor(contrib, m, 64);
    if ((t & 63) == 0) red[t >> 6] = contrib;
    __syncthreads();
    if (t == 0) {
        float p = red[0] + red[1] + red[2] + red[3];
        float y2 = fmaxf(p + b2[0], 0.0f);
        float y3 = fmaxf(W3[0] * y2 + b3[0], 0.0f);
        out[e] = 1.0f / (1.0f + __expf(-y3));
    }
}

extern "C" void kernel_launch(void* const* d_in, const int* in_sizes, int n_in,
                              void* d_out, int out_size, void* d_ws, size_t ws_size,
                              hipStream_t stream) {
    const float* h   = (const float*)d_in[0];
    const int*   src = (const int*)d_in[1];
    const int*   dst = (const int*)d_in[2];
    const float* W1  = (const float*)d_in[3];
    const float* b1  = (const float*)d_in[4];
    const float* W2  = (const float*)d_in[5];
    const float* b2  = (const float*)d_in[6];
    const float* W3  = (const float*)d_in[7];
    const float* b3  = (const float*)d_in[8];
    float* out = (float*)d_out;

    const int N = in_sizes[0] / HID;   // 100000
    const int E = in_sizes[1];         // 500000

    const size_t ab_bytes = (size_t)N * 256 * sizeof(unsigned short);
    if (ab_bytes <= ws_size) {
        unsigned short* AB = (unsigned short*)d_ws;
        const int node_tiles = (N + 15) / 16;
        const int nblocks = (node_tiles + NT_PER_BLOCK - 1) / NT_PER_BLOCK;
        node_stage_kernel<<<nblocks, 256, 0, stream>>>(h, W1, b1, AB, N);
        edge_stage_kernel<<<(E + 15) / 16, 256, 0, stream>>>(AB, src, dst, W2, b2, W3, b3, out, E);
    } else {
        edge_direct_kernel<<<E, 256, 0, stream>>>(h, src, dst, W1, b1, W2, b2, W3, b3, out, E);
    }
}

// Round 5
// 152.345 us; speedup vs baseline: 1.1052x; 1.1052x over previous
//
#include <hip/hip_runtime.h>
#include <hip/hip_bf16.h>

// h:[N,128] f32, src/dst:[E] i32, W1:[128,256] f32, b1:[128] f32, W2:[1,128] f32,
// b2,W3,b3: scalars f32  -> out:[E] f32
// Factorization: W1@concat(h[s],h[d]) = W1[:,:128]@h[s] + W1[:,128:]@h[d]
// Stage 0 (prep): W1 f32 -> fragment-ordered bf16 table (64 KB) + bias256 f32
//   table in d_ws. Done once per launch (~3 us); kills the per-block cvt
//   prologue that was ~40% of node-stage VALU (R4 post-mortem).
// Stage 1 (per node, MFMA bf16): AB[n][0:128] = W1[:,:128]@h[n] + b1 ;
//   AB[n][128:256] = W1[:,128:]@h[n].  AB stored bf16 (51.2 MB).
// Stage 2 (per edge): out = sigmoid(relu(W3*relu(W2 . relu(A[s]+B[d]) + b2) + b3))

#define HID 128

using short8 = __attribute__((ext_vector_type(8))) short;  // 8 bf16 = 4 VGPRs
using f32x4  = __attribute__((ext_vector_type(4))) float;

typedef unsigned int uint32;

static __device__ __forceinline__ unsigned short f2bf(float f) {  // RNE f32->bf16
    uint32 u = __float_as_uint(f);
    u += 0x7fffu + ((u >> 16) & 1u);
    return (unsigned short)(u >> 16);
}
static __device__ __forceinline__ uint32 pk2(float a, float b) {
    return ((uint32)f2bf(a)) | (((uint32)f2bf(b)) << 16);
}
static __device__ __forceinline__ float bflo(uint32 u) { return __uint_as_float(u << 16); }
static __device__ __forceinline__ float bfhi(uint32 u) { return __uint_as_float(u & 0xffff0000u); }

// ---------------------------------------------------------------------------
// Stage 0: weight prep. wtab layout: frag widx=(wave*4+ot)*4+ks (0..63),
//   wtab[(widx*64 + lane)*8 + j] = bf16(W1[row][col+j]),
//   o=wave*64+ot*16+(lane&15), row=o&127, col=(o>=128?128:0)+ks*32+(lane>>4)*8.
// bias256[o] = (o<128) ? b1[o] : 0.
// ---------------------------------------------------------------------------
__global__ __launch_bounds__(256) void prep_kernel(
    const float* __restrict__ W1,   // [128,256]
    const float* __restrict__ b1,   // [128]
    unsigned short* __restrict__ wtab,  // [64*64*8]
    float* __restrict__ bias256)        // [256]
{
    const int idx  = blockIdx.x * 256 + threadIdx.x;  // 0..4095
    const int widx = idx >> 6;
    const int lane = idx & 63;
    const int wave = widx >> 4;
    const int ot   = (widx >> 2) & 3;
    const int ks   = widx & 3;
    const int o    = wave * 64 + ot * 16 + (lane & 15);
    const int row  = o & 127;
    const int col  = ((o >= 128) ? 128 : 0) + ks * 32 + (lane >> 4) * 8;
    const float* p = W1 + row * 256 + col;
    float4 f0 = *(const float4*)p;
    float4 f1 = *(const float4*)(p + 4);
    uint4 st;
    st.x = pk2(f0.x, f0.y);
    st.y = pk2(f0.z, f0.w);
    st.z = pk2(f1.x, f1.y);
    st.w = pk2(f1.z, f1.w);
    *(uint4*)(wtab + (size_t)idx * 8) = st;

    if (idx < 256) bias256[idx] = (idx < 128) ? b1[idx] : 0.0f;
}

// ---------------------------------------------------------------------------
// Stage 1 (v2): node GEMM via MFMA, weights pre-converted.
// mfma_f32_16x16x32_bf16 (m89-verified): A[m=lane&15][k=quad*8+j],
//   B[k=quad*8+j][n=lane&15], C/D col=lane&15 (node), row=quad*4+reg (output).
// Double-buffered LDS h tile + register prefetch; one barrier/iter.
// LDS: row r, ch-block j (8ch=16B) at r*256+((j^r)*8): XOR swizzle, b128 ops.
// ---------------------------------------------------------------------------
#define NT_PER_BLOCK 4  // 16-node tiles per block

__global__ __launch_bounds__(256) void node_stage_v2_kernel(
    const float* __restrict__ h,            // [N,128]
    const unsigned short* __restrict__ wtab,// [64*64*8] bf16 frag table
    const float* __restrict__ bias256,      // [256]
    unsigned short* __restrict__ AB,        // [N,256] bf16 bits out
    int N)
{
    __shared__ unsigned short hs[2][16 * 256];  // 2 x 8 KB double buffer

    const int t    = threadIdx.x;
    const int lane = t & 63;
    const int wave = t >> 6;     // 0..3 -> output group wave*64
    const int c    = lane & 15;
    const int q    = lane >> 4;

    // Prologue: coalesced frag loads, no conversion.
    short8 vfrag[4][4];
    float4 bias[4];
#pragma unroll
    for (int ot = 0; ot < 4; ++ot) {
#pragma unroll
        for (int ks = 0; ks < 4; ++ks) {
            int widx = (wave * 4 + ot) * 4 + ks;
            vfrag[ot][ks] = *(const short8*)(wtab + ((size_t)widx * 64 + lane) * 8);
        }
        bias[ot] = *(const float4*)(bias256 + wave * 64 + ot * 16 + q * 4);
    }

    const int sr = t >> 4;   // staging row 0..15
    const int sj = t & 15;   // staging ch-block 0..15
    const int ntiles = N >> 4;            // N is a multiple of 16
    const int nt0 = blockIdx.x * NT_PER_BLOCK;
    if (nt0 >= ntiles) return;

    // Prologue: stage tile nt0 into buffer 0.
    {
        const float* p = h + (size_t)(nt0 * 16 + sr) * HID + sj * 8;
        float4 f0 = *(const float4*)p;
        float4 f1 = *(const float4*)(p + 4);
        uint4 st;
        st.x = pk2(f0.x, f0.y);
        st.y = pk2(f0.z, f0.w);
        st.z = pk2(f1.x, f1.y);
        st.w = pk2(f1.z, f1.w);
        *(uint4*)(hs[0] + sr * 256 + ((sj ^ sr) * 8)) = st;
    }

#pragma unroll
    for (int it = 0; it < NT_PER_BLOCK; ++it) {
        const int tile = nt0 + it;
        if (tile >= ntiles) break;
        __syncthreads();

        // Issue next tile's global loads early (hide HBM latency under MFMA).
        const bool have_next = (it + 1 < NT_PER_BLOCK) && (tile + 1 < ntiles);
        float4 g0, g1;
        if (have_next) {
            const float* p = h + (size_t)((tile + 1) * 16 + sr) * HID + sj * 8;
            g0 = *(const float4*)p;
            g1 = *(const float4*)(p + 4);
        }

        short8 hfrag[4];
#pragma unroll
        for (int ks = 0; ks < 4; ++ks) {
            int blk = (ks * 4 + q) ^ c;  // xor-unswizzle
            hfrag[ks] = *(const short8*)(hs[it & 1] + c * 256 + blk * 8);
        }

        f32x4 acc[4];
#pragma unroll
        for (int ot = 0; ot < 4; ++ot) acc[ot] = (f32x4){0.f, 0.f, 0.f, 0.f};

#pragma unroll
        for (int ks = 0; ks < 4; ++ks)
#pragma unroll
            for (int ot = 0; ot < 4; ++ot)
                acc[ot] = __builtin_amdgcn_mfma_f32_16x16x32_bf16(
                    vfrag[ot][ks], hfrag[ks], acc[ot], 0, 0, 0);

        const int node = tile * 16 + c;
#pragma unroll
        for (int ot = 0; ot < 4; ++ot) {
            int o_base = wave * 64 + ot * 16 + q * 4;
            uint2 st;
            st.x = pk2(acc[ot][0] + bias[ot].x, acc[ot][1] + bias[ot].y);
            st.y = pk2(acc[ot][2] + bias[ot].z, acc[ot][3] + bias[ot].w);
            *(uint2*)(AB + (size_t)node * 256 + o_base) = st;
        }

        // Stage prefetched tile into the other buffer (post-barrier: safe).
        if (have_next) {
            uint4 st;
            st.x = pk2(g0.x, g0.y);
            st.y = pk2(g0.z, g0.w);
            st.z = pk2(g1.x, g1.y);
            st.w = pk2(g1.z, g1.w);
            *(uint4*)(hs[(it + 1) & 1] + sr * 256 + ((sj ^ sr) * 8)) = st;
        }
    }
}

// ---------------------------------------------------------------------------
// Stage 1 (v1, fallback if ws only fits AB): in-kernel weight conversion.
// ---------------------------------------------------------------------------
__global__ __launch_bounds__(256) void node_stage_kernel(
    const float* __restrict__ h,
    const float* __restrict__ W1,
    const float* __restrict__ b1,
    unsigned short* __restrict__ AB,
    int N)
{
    __shared__ unsigned short hs[2][16 * 256];

    const int t    = threadIdx.x;
    const int lane = t & 63;
    const int wave = t >> 6;
    const int c    = lane & 15;
    const int q    = lane >> 4;

    short8 vfrag[4][4];
    float  bias[4][4];
#pragma unroll
    for (int ot = 0; ot < 4; ++ot) {
#pragma unroll
        for (int ks = 0; ks < 4; ++ks) {
            int o   = wave * 64 + ot * 16 + c;
            int row = o & 127;
            int col = ((o >= 128) ? 128 : 0) + ks * 32 + q * 8;
            const float* p = W1 + row * 256 + col;
            float4 f0 = *(const float4*)p;
            float4 f1 = *(const float4*)(p + 4);
            short8 v;
            v[0] = (short)f2bf(f0.x); v[1] = (short)f2bf(f0.y);
            v[2] = (short)f2bf(f0.z); v[3] = (short)f2bf(f0.w);
            v[4] = (short)f2bf(f1.x); v[5] = (short)f2bf(f1.y);
            v[6] = (short)f2bf(f1.z); v[7] = (short)f2bf(f1.w);
            vfrag[ot][ks] = v;
        }
#pragma unroll
        for (int r = 0; r < 4; ++r) {
            int o = wave * 64 + ot * 16 + q * 4 + r;
            bias[ot][r] = (o < 128) ? b1[o] : 0.0f;
        }
    }

    const int sr = t >> 4;
    const int sj = t & 15;
    const int ntiles = N >> 4;
    const int nt0 = blockIdx.x * NT_PER_BLOCK;
    if (nt0 >= ntiles) return;

    {
        const float* p = h + (size_t)(nt0 * 16 + sr) * HID + sj * 8;
        float4 f0 = *(const float4*)p;
        float4 f1 = *(const float4*)(p + 4);
        uint4 st;
        st.x = pk2(f0.x, f0.y);
        st.y = pk2(f0.z, f0.w);
        st.z = pk2(f1.x, f1.y);
        st.w = pk2(f1.z, f1.w);
        *(uint4*)(hs[0] + sr * 256 + ((sj ^ sr) * 8)) = st;
    }

#pragma unroll
    for (int it = 0; it < NT_PER_BLOCK; ++it) {
        const int tile = nt0 + it;
        if (tile >= ntiles) break;
        __syncthreads();

        const bool have_next = (it + 1 < NT_PER_BLOCK) && (tile + 1 < ntiles);
        float4 g0, g1;
        if (have_next) {
            const float* p = h + (size_t)((tile + 1) * 16 + sr) * HID + sj * 8;
            g0 = *(const float4*)p;
            g1 = *(const float4*)(p + 4);
        }

        short8 hfrag[4];
#pragma unroll
        for (int ks = 0; ks < 4; ++ks) {
            int blk = (ks * 4 + q) ^ c;
            hfrag[ks] = *(const short8*)(hs[it & 1] + c * 256 + blk * 8);
        }

        f32x4 acc[4];
#pragma unroll
        for (int ot = 0; ot < 4; ++ot) acc[ot] = (f32x4){0.f, 0.f, 0.f, 0.f};

#pragma unroll
        for (int ks = 0; ks < 4; ++ks)
#pragma unroll
            for (int ot = 0; ot < 4; ++ot)
                acc[ot] = __builtin_amdgcn_mfma_f32_16x16x32_bf16(
                    vfrag[ot][ks], hfrag[ks], acc[ot], 0, 0, 0);

        const int node = tile * 16 + c;
#pragma unroll
        for (int ot = 0; ot < 4; ++ot) {
            int o_base = wave * 64 + ot * 16 + q * 4;
            uint2 st;
            st.x = pk2(acc[ot][0] + bias[ot][0], acc[ot][1] + bias[ot][1]);
            st.y = pk2(acc[ot][2] + bias[ot][2], acc[ot][3] + bias[ot][3]);
            *(uint2*)(AB + (size_t)node * 256 + o_base) = st;
        }

        if (have_next) {
            uint4 st;
            st.x = pk2(g0.x, g0.y);
            st.y = pk2(g0.z, g0.w);
            st.z = pk2(g1.x, g1.y);
            st.w = pk2(g1.z, g1.w);
            *(uint4*)(hs[(it + 1) & 1] + sr * 256 + ((sj ^ sr) * 8)) = st;
        }
    }
}

// ---------------------------------------------------------------------------
// Stage 2: 4 edges per wave, 16 lanes per edge; lane handles 8 channels via
// one uint4 (16B) load each from A-part and B-part. Reduce = 4 xor-shuffles
// shared across the 4 edges; tail once per 16-lane group.
// ---------------------------------------------------------------------------
__global__ __launch_bounds__(256) void edge_stage_kernel(
    const unsigned short* __restrict__ AB,  // [N,256] bf16 bits
    const int* __restrict__ src,
    const int* __restrict__ dst,
    const float* __restrict__ W2,   // [128]
    const float* __restrict__ b2,   // [1]
    const float* __restrict__ W3,   // [1]
    const float* __restrict__ b3,   // [1]
    float* __restrict__ out,        // [E]
    int E)
{
    const int lane = threadIdx.x & 63;
    const int wave = threadIdx.x >> 6;
    const int sub  = lane & 15;     // lane within edge group
    const int eg   = lane >> 4;     // edge slot 0..3 in this wave
    const int e    = blockIdx.x * 16 + wave * 4 + eg;
    if (e >= E) return;

    const int s = src[e];
    const int d = dst[e];

    const uint4 ua = *(const uint4*)(AB + (size_t)s * 256 + sub * 8);
    const uint4 ub = *(const uint4*)(AB + (size_t)d * 256 + 128 + sub * 8);
    const float4 w0 = *(const float4*)(W2 + sub * 8);
    const float4 w1 = *(const float4*)(W2 + sub * 8 + 4);

    float p;
    {
        float t0 = fmaxf(bflo(ua.x) + bflo(ub.x), 0.0f);
        float t1 = fmaxf(bfhi(ua.x) + bfhi(ub.x), 0.0f);
        float t2 = fmaxf(bflo(ua.y) + bflo(ub.y), 0.0f);
        float t3 = fmaxf(bfhi(ua.y) + bfhi(ub.y), 0.0f);
        float t4 = fmaxf(bflo(ua.z) + bflo(ub.z), 0.0f);
        float t5 = fmaxf(bfhi(ua.z) + bfhi(ub.z), 0.0f);
        float t6 = fmaxf(bflo(ua.w) + bflo(ub.w), 0.0f);
        float t7 = fmaxf(bfhi(ua.w) + bfhi(ub.w), 0.0f);
        p  = t0 * w0.x;
        p  = fmaf(t1, w0.y, p);
        p  = fmaf(t2, w0.z, p);
        p  = fmaf(t3, w0.w, p);
        p  = fmaf(t4, w1.x, p);
        p  = fmaf(t5, w1.y, p);
        p  = fmaf(t6, w1.z, p);
        p  = fmaf(t7, w1.w, p);
    }

#pragma unroll
    for (int m = 8; m >= 1; m >>= 1) p += __shfl_xor(p, m, 64);

    if (sub == 0) {
        float y2 = fmaxf(p + b2[0], 0.0f);
        float y3 = fmaxf(W3[0] * y2 + b3[0], 0.0f);
        out[e] = 1.0f / (1.0f + __expf(-y3));
    }
}

// ---------------------------------------------------------------------------
// Fallback (ws too small for AB): direct per-edge MLP, fp32. Correct, slow.
// ---------------------------------------------------------------------------
__global__ __launch_bounds__(256) void edge_direct_kernel(
    const float* __restrict__ h,
    const int* __restrict__ src,
    const int* __restrict__ dst,
    const float* __restrict__ W1,
    const float* __restrict__ b1,
    const float* __restrict__ W2,
    const float* __restrict__ b2,
    const float* __restrict__ W3,
    const float* __restrict__ b3,
    float* __restrict__ out,
    int E)
{
    __shared__ float x[256];
    __shared__ float red[4];
    const int e = blockIdx.x;
    if (e >= E) return;
    const int t = threadIdx.x;
    const int s = src[e];
    const int d = dst[e];

    if (t < 128) x[t] = h[(size_t)s * HID + t];
    else         x[t] = h[(size_t)d * HID + (t - 128)];
    __syncthreads();

    float contrib = 0.0f;
    if (t < 128) {
        float acc = b1[t];
        const float* wr = W1 + t * 256;
        for (int k = 0; k < 256; ++k) acc = fmaf(wr[k], x[k], acc);
        contrib = fmaxf(acc, 0.0f) * W2[t];
    }
#pragma unroll
    for (int m = 32; m >= 1; m >>= 1) contrib += __shfl_xor(contrib, m, 64);
    if ((t & 63) == 0) red[t >> 6] = contrib;
    __syncthreads();
    if (t == 0) {
        float p = red[0] + red[1] + red[2] + red[3];
        float y2 = fmaxf(p + b2[0], 0.0f);
        float y3 = fmaxf(W3[0] * y2 + b3[0], 0.0f);
        out[e] = 1.0f / (1.0f + __expf(-y3));
    }
}

extern "C" void kernel_launch(void* const* d_in, const int* in_sizes, int n_in,
                              void* d_out, int out_size, void* d_ws, size_t ws_size,
                              hipStream_t stream) {
    const float* h   = (const float*)d_in[0];
    const int*   src = (const int*)d_in[1];
    const int*   dst = (const int*)d_in[2];
    const float* W1  = (const float*)d_in[3];
    const float* b1  = (const float*)d_in[4];
    const float* W2  = (const float*)d_in[5];
    const float* b2  = (const float*)d_in[6];
    const float* W3  = (const float*)d_in[7];
    const float* b3  = (const float*)d_in[8];
    float* out = (float*)d_out;

    const int N = in_sizes[0] / HID;   // 100000
    const int E = in_sizes[1];         // 500000

    const size_t ab_bytes  = (size_t)N * 256 * sizeof(unsigned short);
    const size_t wtab_off  = (ab_bytes + 255) & ~(size_t)255;
    const size_t wtab_bytes = (size_t)64 * 64 * 8 * sizeof(unsigned short);  // 64 KB
    const size_t bias_off  = wtab_off + wtab_bytes;
    const size_t need_v2   = bias_off + 256 * sizeof(float);

    const int node_tiles = (N + 15) / 16;
    const int nblocks = (node_tiles + NT_PER_BLOCK - 1) / NT_PER_BLOCK;

    if (need_v2 <= ws_size) {
        unsigned short* AB   = (unsigned short*)d_ws;
        unsigned short* wtab = (unsigned short*)((char*)d_ws + wtab_off);
        float* bias256       = (float*)((char*)d_ws + bias_off);
        prep_kernel<<<16, 256, 0, stream>>>(W1, b1, wtab, bias256);
        node_stage_v2_kernel<<<nblocks, 256, 0, stream>>>(h, wtab, bias256, AB, N);
        edge_stage_kernel<<<(E + 15) / 16, 256, 0, stream>>>(AB, src, dst, W2, b2, W3, b3, out, E);
    } else if (ab_bytes <= ws_size) {
        unsigned short* AB = (unsigned short*)d_ws;
        node_stage_kernel<<<nblocks, 256, 0, stream>>>(h, W1, b1, AB, N);
        edge_stage_kernel<<<(E + 15) / 16, 256, 0, stream>>>(AB, src, dst, W2, b2, W3, b3, out, E);
    } else {
        edge_direct_kernel<<<E, 256, 0, stream>>>(h, src, dst, W1, b1, W2, b2, W3, b3, out, E);
    }
}